// Round 3
// baseline (714.030 us; speedup 1.0000x reference)
//
#include <hip/hip_runtime.h>
#include <hip/hip_fp16.h>
#include <math.h>

#define ACT_SCALE_F (1.0f / 12.0f)
#define LOG2E_F 1.44269504088896340736f
#define LN2_F   0.69314718055994530942f

// ws layout (floats), total 4514:
// [0..1023]    spA1T : spA1T[r*32+o] = sp(A1[o][r])   (fwd matvec 1)
// [1024..2047] spA2T : sp(A2[o][r])                    (fwd matvec 2)
// [2048..3071] spA2  : row-major                       (bwd matvec 2)
// [3072..4095] spA1  : row-major                       (bwd matvec 1)
// [4096..4127] spAout[32]
// [4128..4255] Bfq: {Bf_w[2i], Bf_w[2i+1], Bf_b[i], 0} x32
// [4256..4383] B1q
// [4384..4511] B2q
// [4512..4513] grad_ref (Bo_w omitted on both sides -> cancels)
#define WTOT 4514

// softplus + sigmoid from one exp2: t = e^{-|x|}
__device__ __forceinline__ void sp_sig(float x, float& sp, float& sig) {
    float t = __builtin_amdgcn_exp2f(-fabsf(x) * LOG2E_F);
    float u = 1.0f + t;
    float r = __builtin_amdgcn_rcpf(u);
    sp = fmaf(__builtin_amdgcn_logf(u), LN2_F, fmaxf(x, 0.0f));
    sig = (x >= 0.0f) ? r : t * r;
}

__device__ __forceinline__ float sp_only(float x) {
    float t = __builtin_amdgcn_exp2f(-fabsf(x) * LOG2E_F);
    return fmaf(__builtin_amdgcn_logf(1.0f + t), LN2_F, fmaxf(x, 0.0f));
}

__device__ __forceinline__ float sig_only(float x) {
    float t = __builtin_amdgcn_exp2f(-fabsf(x) * LOG2E_F);
    float r = __builtin_amdgcn_rcpf(1.0f + t);
    return (x >= 0.0f) ? r : t * r;
}

__global__ void prep_kernel(const float* __restrict__ Bf_w, const float* __restrict__ Bf_b,
                            const float* __restrict__ A1,
                            const float* __restrict__ B1_w, const float* __restrict__ B1_b,
                            const float* __restrict__ A2,
                            const float* __restrict__ B2_w, const float* __restrict__ B2_b,
                            const float* __restrict__ A_out,
                            float* __restrict__ ws)
{
    __shared__ float sA1[1024], sA2[1024], sAout[32];
    __shared__ float vbufA[32], vbufB[32];
    __shared__ float part0[32], part1[32];
    const int tid = threadIdx.x;  // 64 threads, 1 block

    for (int e = tid; e < 1024; e += 64) {
        const int i = e >> 5, j = e & 31;
        float w1 = sp_only(A1[e]);
        float w2 = sp_only(A2[e]);
        sA1[e] = w1;
        sA2[e] = w2;
        ws[j * 32 + i] = w1;          // spA1T
        ws[1024 + j * 32 + i] = w2;   // spA2T
        ws[2048 + e] = w2;            // spA2
        ws[3072 + e] = w1;            // spA1
    }
    if (tid < 32) {
        float ao = sp_only(A_out[tid]);
        sAout[tid] = ao;
        ws[4096 + tid] = ao;
        ws[4128 + 4 * tid]     = Bf_w[2 * tid];
        ws[4128 + 4 * tid + 1] = Bf_w[2 * tid + 1];
        ws[4128 + 4 * tid + 2] = Bf_b[tid];
        ws[4128 + 4 * tid + 3] = 0.f;
        ws[4256 + 4 * tid]     = B1_w[2 * tid];
        ws[4256 + 4 * tid + 1] = B1_w[2 * tid + 1];
        ws[4256 + 4 * tid + 2] = B1_b[tid];
        ws[4256 + 4 * tid + 3] = 0.f;
        ws[4384 + 4 * tid]     = B2_w[2 * tid];
        ws[4384 + 4 * tid + 1] = B2_w[2 * tid + 1];
        ws[4384 + 4 * tid + 2] = B2_b[tid];
        ws[4384 + 4 * tid + 3] = 0.f;
    }
    __syncthreads();

    const int i = tid;
    float su1 = 0.f, g1 = 0.f, sb1 = 0.f;
    if (tid < 32) {
        float h0;
        sp_sig(Bf_b[i], h0, su1);
        vbufA[i] = h0;
    }
    __syncthreads();
    if (tid < 32) {
        float a1 = 0.f;
        for (int j = 0; j < 32; ++j) a1 = fmaf(vbufA[j], sA1[i * 32 + j], a1);
        float s1, sa1; sp_sig(a1, s1, sa1);
        g1 = 2.0f * ACT_SCALE_F * s1 * sa1;
        float spb1; sp_sig(B1_b[i], spb1, sb1);
        vbufB[i] = fmaf(ACT_SCALE_F * s1, s1, spb1);   // z1
    }
    __syncthreads();
    if (tid < 32) {
        float a2 = 0.f;
        for (int j = 0; j < 32; ++j) a2 = fmaf(vbufB[j], sA2[i * 32 + j], a2);
        float s2, sa2; sp_sig(a2, s2, sa2);
        float g2 = 2.0f * ACT_SCALE_F * s2 * sa2;
        float sb2 = sig_only(B2_b[i]);
        float ao = sAout[i];
        part0[i] = ao * sb2 * B2_w[i * 2 + 0];
        part1[i] = ao * sb2 * B2_w[i * 2 + 1];
        vbufA[i] = ao * g2;   // v2
    }
    __syncthreads();
    if (tid < 32) {
        float dz1 = 0.f;
        for (int ii = 0; ii < 32; ++ii) dz1 = fmaf(vbufA[ii], sA2[ii * 32 + i], dz1);
        part0[i] += dz1 * sb1 * B1_w[i * 2 + 0];
        part1[i] += dz1 * sb1 * B1_w[i * 2 + 1];
        vbufB[i] = dz1 * g1;   // v1
    }
    __syncthreads();
    if (tid < 32) {
        float dh0 = 0.f;
        for (int ii = 0; ii < 32; ++ii) dh0 = fmaf(vbufB[ii], sA1[ii * 32 + i], dh0);
        part0[i] += dh0 * su1 * Bf_w[i * 2 + 0];
        part1[i] += dh0 * su1 * Bf_w[i * 2 + 1];
    }
    __syncthreads();
    if (tid == 0) {
        float r0 = 0.f, r1 = 0.f;
        for (int j = 0; j < 32; ++j) { r0 += part0[j]; r1 += part1[j]; }
        ws[4512] = r0;
        ws[4513] = r1;
    }
}

// f32-accumulate matvec: acc[o] = sum_r vb[r] * w[r*32+o]; vb fp16 in LDS, w f32 in LDS
__device__ __forceinline__ void matvec32(const float* __restrict__ w_base,
                                         const __half* __restrict__ vb,
                                         float* __restrict__ acc)
{
    #pragma unroll
    for (int o = 0; o < 32; ++o) acc[o] = 0.f;
    #pragma unroll 4
    for (int r = 0; r < 32; ++r) {
        const float v = __half2float(vb[r]);
        const float* __restrict__ w = w_base + r * 32;
        #pragma unroll
        for (int o = 0; o < 32; ++o) acc[o] = fmaf(v, w[o], acc[o]);
    }
}

__global__ void __launch_bounds__(256) icnn_main(
    const float* __restrict__ eps,
    const float* __restrict__ ws,
    float* __restrict__ out, int n)
{
    __shared__ float sW[WTOT];
    __shared__ __half vbh[256 * 33];
    const int tid = threadIdx.x;

    for (int e = tid; e < WTOT; e += 256) sW[e] = ws[e];
    __syncthreads();

    int idx = blockIdx.x * 256 + tid;
    if (idx >= n) idx = n - 1;            // branchless clamp: uniform control flow

    const float e11 = eps[3 * idx + 0];
    const float e22 = eps[3 * idx + 1];
    const float e12 = eps[3 * idx + 2];
    const float I1 = e11 + e22;
    const float I2 = e11 * e11 + 2.f * e12 * e12 + e22 * e22;

    const float* __restrict__ A1T  = sW;
    const float* __restrict__ A2T  = sW + 1024;
    const float* __restrict__ A2r  = sW + 2048;
    const float* __restrict__ A1r  = sW + 3072;
    const float* __restrict__ Aout = sW + 4096;
    const float* __restrict__ Bfq  = sW + 4128;
    const float* __restrict__ B1q  = sW + 4256;
    const float* __restrict__ B2q  = sW + 4384;
    const float gr0 = sW[4512];
    const float gr1 = sW[4513];

    __half* __restrict__ vb = vbh + tid * 33;

    __half2 su1p[16], g1p[16], sb1p[16];   // packed backward multipliers (g1 pre-scaled /64)
    float acc[32];

    // ---- layer 0: h0 = sp(z0 @ Bf_w.T + Bf_b) ----
    #pragma unroll
    for (int p = 0; p < 16; ++p) {
        const int i = 2 * p;
        const float4 qa = *(const float4*)&Bfq[4 * i];
        const float4 qb = *(const float4*)&Bfq[4 * i + 4];
        float u1a = fmaf(I1, qa.x, fmaf(I2, qa.y, qa.z));
        float u1b = fmaf(I1, qb.x, fmaf(I2, qb.y, qb.z));
        float h0a, sua, h0b, sub;
        sp_sig(u1a, h0a, sua);
        sp_sig(u1b, h0b, sub);
        su1p[p] = __floats2half2_rn(sua, sub);
        vb[i]     = __float2half(h0a);
        vb[i + 1] = __float2half(h0b);
    }

    // ---- a1 = spA1 @ h0 ----
    matvec32(A1T, vb, acc);

    // ---- layer 1 elementwise ----
    #pragma unroll
    for (int p = 0; p < 16; ++p) {
        const int i = 2 * p;
        float s1a, saa, s1b, sab;
        sp_sig(acc[i], s1a, saa);
        sp_sig(acc[i + 1], s1b, sab);
        g1p[p] = __floats2half2_rn((2.0f * ACT_SCALE_F / 64.0f) * s1a * saa,
                                   (2.0f * ACT_SCALE_F / 64.0f) * s1b * sab);
        const float4 qa = *(const float4*)&B1q[4 * i];
        const float4 qb = *(const float4*)&B1q[4 * i + 4];
        float b1a = fmaf(I1, qa.x, fmaf(I2, qa.y, qa.z));
        float b1b = fmaf(I1, qb.x, fmaf(I2, qb.y, qb.z));
        float spb1a, sba, spb1b, sbb;
        sp_sig(b1a, spb1a, sba);
        sp_sig(b1b, spb1b, sbb);
        sb1p[p] = __floats2half2_rn(sba, sbb);
        vb[i]     = __float2half(fmaf(ACT_SCALE_F * s1a, s1a, spb1a));   // z1
        vb[i + 1] = __float2half(fmaf(ACT_SCALE_F * s1b, s1b, spb1b));
    }

    // ---- a2 = spA2 @ z1 ----
    matvec32(A2T, vb, acc);

    // ---- layer 2 elementwise + B2_w grad contribution + v2 ----
    float gx0 = 0.f, gx1 = 0.f;
    #pragma unroll
    for (int i = 0; i < 32; ++i) {
        float s2, sa2;
        sp_sig(acc[i], s2, sa2);
        float g2 = (2.0f * ACT_SCALE_F) * s2 * sa2;
        const float4 q = *(const float4*)&B2q[4 * i];
        float b2 = fmaf(I1, q.x, fmaf(I2, q.y, q.z));
        float sb2 = sig_only(b2);
        float ao = Aout[i];
        float t = ao * sb2;
        gx0 = fmaf(t, q.x, gx0);
        gx1 = fmaf(t, q.y, gx1);
        vb[i] = __float2half(ao * g2);   // v2  (<= ~1500, fits fp16)
    }

    // ---- backward: dz1_j = sum_i v2_i * spA2[i][j] ----
    matvec32(A2r, vb, acc);

    #pragma unroll
    for (int p = 0; p < 16; ++p) {
        const int j = 2 * p;
        const float4 qa = *(const float4*)&B1q[4 * j];
        const float4 qb = *(const float4*)&B1q[4 * j + 4];
        float sba = __low2float(sb1p[p]), sbb = __high2float(sb1p[p]);
        float ga  = __low2float(g1p[p]),  gb  = __high2float(g1p[p]);
        float ta = acc[j] * sba, tb = acc[j + 1] * sbb;
        gx0 = fmaf(ta, qa.x, fmaf(tb, qb.x, gx0));
        gx1 = fmaf(ta, qa.y, fmaf(tb, qb.y, gx1));
        vb[j]     = __float2half(acc[j] * ga);       // v1/64 (fits fp16)
        vb[j + 1] = __float2half(acc[j + 1] * gb);
    }

    // ---- backward: dh0_j = sum_i v1_i * spA1[i][j]  (scaled by 1/64) ----
    matvec32(A1r, vb, acc);

    float gxf0 = 0.f, gxf1 = 0.f;
    #pragma unroll
    for (int p = 0; p < 16; ++p) {
        const int j = 2 * p;
        const float4 qa = *(const float4*)&Bfq[4 * j];
        const float4 qb = *(const float4*)&Bfq[4 * j + 4];
        float sua = __low2float(su1p[p]), sub = __high2float(su1p[p]);
        float ta = acc[j] * sua, tb = acc[j + 1] * sub;
        gxf0 = fmaf(ta, qa.x, fmaf(tb, qb.x, gxf0));
        gxf1 = fmaf(ta, qa.y, fmaf(tb, qb.y, gxf1));
    }
    gx0 = fmaf(64.f, gxf0, gx0);    // undo 1/64 scale on layer-0 path
    gx1 = fmaf(64.f, gxf1, gx1);

    const float dI1 = gx0 - gr0;
    const float dI2 = gx1 - gr1;
    out[3 * idx + 0] = fmaf(2.f * e11, dI2, dI1);
    out[3 * idx + 1] = fmaf(2.f * e22, dI2, dI1);
    out[3 * idx + 2] = 2.f * e12 * dI2;
}

extern "C" void kernel_launch(void* const* d_in, const int* in_sizes, int n_in,
                              void* d_out, int out_size, void* d_ws, size_t ws_size,
                              hipStream_t stream)
{
    const float* eps   = (const float*)d_in[0];
    const float* Bf_w  = (const float*)d_in[1];
    const float* Bf_b  = (const float*)d_in[2];
    const float* A1    = (const float*)d_in[3];
    const float* B1_w  = (const float*)d_in[4];
    const float* B1_b  = (const float*)d_in[5];
    const float* A2    = (const float*)d_in[6];
    const float* B2_w  = (const float*)d_in[7];
    const float* B2_b  = (const float*)d_in[8];
    const float* A_out = (const float*)d_in[9];
    // d_in[10] = Bo_w (cancels in grads - grad_ref), d_in[11] = Bo_b (no grad)

    float* ws  = (float*)d_ws;
    float* out = (float*)d_out;
    const int n = in_sizes[0] / 3;

    prep_kernel<<<1, 64, 0, stream>>>(Bf_w, Bf_b, A1, B1_w, B1_b, A2, B2_w, B2_b, A_out, ws);
    const int blocks = (n + 255) / 256;
    icnn_main<<<blocks, 256, 0, stream>>>(eps, ws, out, n);
}

// Round 4
// 231.735 us; speedup vs baseline: 3.0812x; 3.0812x over previous
//
#include <hip/hip_runtime.h>
#include <math.h>

#define ACT_SCALE_F (1.0f / 12.0f)
#define LOG2E_F 1.44269504088896340736f
#define LN2_F   0.69314718055994530942f

// ws layout (floats), total 4514:
// [0..1023]    spA1T : spA1T[r*32+o] = sp(A1[o][r])   (fwd matvec 1)
// [1024..2047] spA2T : sp(A2[o][r])                    (fwd matvec 2)
// [2048..3071] spA2  : row-major                       (bwd matvec 2)
// [3072..4095] spA1  : row-major                       (bwd matvec 1)
// [4096..4127] spAout[32]
// [4128..4255] Bfq: {Bf_w[2i], Bf_w[2i+1], Bf_b[i], 0} x32
// [4256..4383] B1q
// [4384..4511] B2q
// [4512..4513] grad_ref (Bo_w omitted on both sides -> cancels)

// softplus + sigmoid from one exp2: t = e^{-|x|}
__device__ __forceinline__ void sp_sig(float x, float& sp, float& sig) {
    float t = __builtin_amdgcn_exp2f(-fabsf(x) * LOG2E_F);
    float u = 1.0f + t;
    float r = __builtin_amdgcn_rcpf(u);
    sp = fmaf(__builtin_amdgcn_logf(u), LN2_F, fmaxf(x, 0.0f));
    sig = (x >= 0.0f) ? r : t * r;
}

__device__ __forceinline__ float sp_only(float x) {
    float t = __builtin_amdgcn_exp2f(-fabsf(x) * LOG2E_F);
    return fmaf(__builtin_amdgcn_logf(1.0f + t), LN2_F, fmaxf(x, 0.0f));
}

__device__ __forceinline__ float sig_only(float x) {
    float t = __builtin_amdgcn_exp2f(-fabsf(x) * LOG2E_F);
    float r = __builtin_amdgcn_rcpf(1.0f + t);
    return (x >= 0.0f) ? r : t * r;
}

__global__ void prep_kernel(const float* __restrict__ Bf_w, const float* __restrict__ Bf_b,
                            const float* __restrict__ A1,
                            const float* __restrict__ B1_w, const float* __restrict__ B1_b,
                            const float* __restrict__ A2,
                            const float* __restrict__ B2_w, const float* __restrict__ B2_b,
                            const float* __restrict__ A_out,
                            float* __restrict__ ws)
{
    __shared__ float sA1[1024], sA2[1024], sAout[32];
    __shared__ float vbufA[32], vbufB[32];
    __shared__ float part0[32], part1[32];
    const int tid = threadIdx.x;  // 64 threads, 1 block

    for (int e = tid; e < 1024; e += 64) {
        const int i = e >> 5, j = e & 31;
        float w1 = sp_only(A1[e]);
        float w2 = sp_only(A2[e]);
        sA1[e] = w1;
        sA2[e] = w2;
        ws[j * 32 + i] = w1;          // spA1T
        ws[1024 + j * 32 + i] = w2;   // spA2T
        ws[2048 + e] = w2;            // spA2
        ws[3072 + e] = w1;            // spA1
    }
    if (tid < 32) {
        float ao = sp_only(A_out[tid]);
        sAout[tid] = ao;
        ws[4096 + tid] = ao;
        ws[4128 + 4 * tid]     = Bf_w[2 * tid];
        ws[4128 + 4 * tid + 1] = Bf_w[2 * tid + 1];
        ws[4128 + 4 * tid + 2] = Bf_b[tid];
        ws[4128 + 4 * tid + 3] = 0.f;
        ws[4256 + 4 * tid]     = B1_w[2 * tid];
        ws[4256 + 4 * tid + 1] = B1_w[2 * tid + 1];
        ws[4256 + 4 * tid + 2] = B1_b[tid];
        ws[4256 + 4 * tid + 3] = 0.f;
        ws[4384 + 4 * tid]     = B2_w[2 * tid];
        ws[4384 + 4 * tid + 1] = B2_w[2 * tid + 1];
        ws[4384 + 4 * tid + 2] = B2_b[tid];
        ws[4384 + 4 * tid + 3] = 0.f;
    }
    __syncthreads();

    const int i = tid;
    float su1 = 0.f, g1 = 0.f, sb1 = 0.f;
    if (tid < 32) {
        float h0;
        sp_sig(Bf_b[i], h0, su1);
        vbufA[i] = h0;
    }
    __syncthreads();
    if (tid < 32) {
        float a1 = 0.f;
        for (int j = 0; j < 32; ++j) a1 = fmaf(vbufA[j], sA1[i * 32 + j], a1);
        float s1, sa1; sp_sig(a1, s1, sa1);
        g1 = 2.0f * ACT_SCALE_F * s1 * sa1;
        float spb1; sp_sig(B1_b[i], spb1, sb1);
        vbufB[i] = fmaf(ACT_SCALE_F * s1, s1, spb1);   // z1
    }
    __syncthreads();
    if (tid < 32) {
        float a2 = 0.f;
        for (int j = 0; j < 32; ++j) a2 = fmaf(vbufB[j], sA2[i * 32 + j], a2);
        float s2, sa2; sp_sig(a2, s2, sa2);
        float g2 = 2.0f * ACT_SCALE_F * s2 * sa2;
        float sb2 = sig_only(B2_b[i]);
        float ao = sAout[i];
        part0[i] = ao * sb2 * B2_w[i * 2 + 0];
        part1[i] = ao * sb2 * B2_w[i * 2 + 1];
        vbufA[i] = ao * g2;   // v2
    }
    __syncthreads();
    if (tid < 32) {
        float dz1 = 0.f;
        for (int ii = 0; ii < 32; ++ii) dz1 = fmaf(vbufA[ii], sA2[ii * 32 + i], dz1);
        part0[i] += dz1 * sb1 * B1_w[i * 2 + 0];
        part1[i] += dz1 * sb1 * B1_w[i * 2 + 1];
        vbufB[i] = dz1 * g1;   // v1
    }
    __syncthreads();
    if (tid < 32) {
        float dh0 = 0.f;
        for (int ii = 0; ii < 32; ++ii) dh0 = fmaf(vbufB[ii], sA1[ii * 32 + i], dh0);
        part0[i] += dh0 * su1 * Bf_w[i * 2 + 0];
        part1[i] += dh0 * su1 * Bf_w[i * 2 + 1];
    }
    __syncthreads();
    if (tid == 0) {
        float r0 = 0.f, r1 = 0.f;
        for (int j = 0; j < 32; ++j) { r0 += part0[j]; r1 += part1[j]; }
        ws[4512] = r0;
        ws[4513] = r1;
    }
}

// acc[o] = sum_r vb[r] * w[r*32+o]; vb f32 in LDS (per-thread), w f32 via uniform s_loads
__device__ __forceinline__ void matvec32(const float* __restrict__ w_base,
                                         const float* __restrict__ vb,
                                         float* __restrict__ acc)
{
    #pragma unroll
    for (int o = 0; o < 32; ++o) acc[o] = 0.f;
    #pragma unroll 4
    for (int r = 0; r < 32; ++r) {
        const float v = vb[r];
        const float* __restrict__ w = w_base + r * 32;
        #pragma unroll
        for (int o = 0; o < 32; ++o) acc[o] = fmaf(v, w[o], acc[o]);
    }
}

__global__ void __launch_bounds__(256) icnn_main(
    const float* __restrict__ eps,
    const float* __restrict__ ws,
    float* __restrict__ out, int n)
{
    __shared__ float vbuf[256 * 33];   // per-thread 32-vec, stride-33 swizzle (2-way alias = free)
    const int tid = threadIdx.x;
    float* __restrict__ vb = &vbuf[tid * 33];

    int idx = blockIdx.x * 256 + tid;
    if (idx >= n) idx = n - 1;         // branchless clamp: uniform control flow

    const float e11 = eps[3 * idx + 0];
    const float e22 = eps[3 * idx + 1];
    const float e12 = eps[3 * idx + 2];
    const float I1 = e11 + e22;
    const float I2 = e11 * e11 + 2.f * e12 * e12 + e22 * e22;

    const float* __restrict__ A1T  = ws;
    const float* __restrict__ A2T  = ws + 1024;
    const float* __restrict__ A2r  = ws + 2048;
    const float* __restrict__ A1r  = ws + 3072;
    const float* __restrict__ Aout = ws + 4096;
    const float* __restrict__ Bfq  = ws + 4128;
    const float* __restrict__ B1q  = ws + 4256;
    const float* __restrict__ B2q  = ws + 4384;

    float acc[32];
    float g1[32];   // only multiplier array kept live (a1 unrecoverable without a matvec)

    // ---- layer 0: h0 = sp(z0 @ Bf_w.T + Bf_b); su1 recomputed in bwd ----
    #pragma unroll
    for (int i = 0; i < 32; ++i) {
        const float4 q = *(const float4*)&Bfq[4 * i];
        vb[i] = sp_only(fmaf(I1, q.x, fmaf(I2, q.y, q.z)));
    }

    // ---- a1 = spA1 @ h0 ----
    matvec32(A1T, vb, acc);

    // ---- layer 1 elementwise: keep g1, recompute sb1 later ----
    #pragma unroll
    for (int i = 0; i < 32; ++i) {
        float s1, sa1;
        sp_sig(acc[i], s1, sa1);
        g1[i] = (2.0f * ACT_SCALE_F) * s1 * sa1;
        const float4 q = *(const float4*)&B1q[4 * i];
        float b1 = fmaf(I1, q.x, fmaf(I2, q.y, q.z));
        vb[i] = fmaf(ACT_SCALE_F * s1, s1, sp_only(b1));   // z1
    }

    // ---- a2 = spA2 @ z1 ----
    matvec32(A2T, vb, acc);

    // ---- layer 2 elementwise + B2_w grad contribution + v2 ----
    float gx0 = 0.f, gx1 = 0.f;
    #pragma unroll
    for (int i = 0; i < 32; ++i) {
        float s2, sa2;
        sp_sig(acc[i], s2, sa2);
        float g2 = (2.0f * ACT_SCALE_F) * s2 * sa2;
        const float4 q = *(const float4*)&B2q[4 * i];
        float sb2 = sig_only(fmaf(I1, q.x, fmaf(I2, q.y, q.z)));
        float t = Aout[i] * sb2;
        gx0 = fmaf(t, q.x, gx0);
        gx1 = fmaf(t, q.y, gx1);
        vb[i] = Aout[i] * g2;   // v2
    }

    // ---- backward: dz1_j = sum_i v2_i * spA2[i][j] ----
    matvec32(A2r, vb, acc);

    #pragma unroll
    for (int j = 0; j < 32; ++j) {
        const float4 q = *(const float4*)&B1q[4 * j];
        float sb1 = sig_only(fmaf(I1, q.x, fmaf(I2, q.y, q.z)));   // recomputed
        float t = acc[j] * sb1;
        gx0 = fmaf(t, q.x, gx0);
        gx1 = fmaf(t, q.y, gx1);
        vb[j] = acc[j] * g1[j];   // v1
    }

    // ---- backward: dh0_j = sum_i v1_i * spA1[i][j] ----
    matvec32(A1r, vb, acc);

    #pragma unroll
    for (int j = 0; j < 32; ++j) {
        const float4 q = *(const float4*)&Bfq[4 * j];
        float su1 = sig_only(fmaf(I1, q.x, fmaf(I2, q.y, q.z)));   // recomputed
        float t = acc[j] * su1;
        gx0 = fmaf(t, q.x, gx0);
        gx1 = fmaf(t, q.y, gx1);
    }

    const float dI1 = gx0 - ws[4512];
    const float dI2 = gx1 - ws[4513];
    out[3 * idx + 0] = fmaf(2.f * e11, dI2, dI1);
    out[3 * idx + 1] = fmaf(2.f * e22, dI2, dI1);
    out[3 * idx + 2] = 2.f * e12 * dI2;
}

extern "C" void kernel_launch(void* const* d_in, const int* in_sizes, int n_in,
                              void* d_out, int out_size, void* d_ws, size_t ws_size,
                              hipStream_t stream)
{
    const float* eps   = (const float*)d_in[0];
    const float* Bf_w  = (const float*)d_in[1];
    const float* Bf_b  = (const float*)d_in[2];
    const float* A1    = (const float*)d_in[3];
    const float* B1_w  = (const float*)d_in[4];
    const float* B1_b  = (const float*)d_in[5];
    const float* A2    = (const float*)d_in[6];
    const float* B2_w  = (const float*)d_in[7];
    const float* B2_b  = (const float*)d_in[8];
    const float* A_out = (const float*)d_in[9];
    // d_in[10] = Bo_w (cancels in grads - grad_ref), d_in[11] = Bo_b (no grad)

    float* ws  = (float*)d_ws;
    float* out = (float*)d_out;
    const int n = in_sizes[0] / 3;

    prep_kernel<<<1, 64, 0, stream>>>(Bf_w, Bf_b, A1, B1_w, B1_b, A2, B2_w, B2_b, A_out, ws);
    const int blocks = (n + 255) / 256;
    icnn_main<<<blocks, 256, 0, stream>>>(eps, ws, out, n);
}

// Round 6
// 192.503 us; speedup vs baseline: 3.7092x; 1.2038x over previous
//
#include <hip/hip_runtime.h>
#include <hip/hip_fp16.h>
#include <math.h>

#define ACT_SCALE_F (1.0f / 12.0f)
#define LOG2E_F 1.44269504088896340736f
#define LN2_F   0.69314718055994530942f

typedef __attribute__((ext_vector_type(8))) _Float16 half8;
typedef __attribute__((ext_vector_type(4))) float f32x4;
typedef __attribute__((ext_vector_type(4))) unsigned int uint4v;

// ws layout:
//  float view:
//   [0..127]   Bfq quads {Bf_w[2i], Bf_w[2i+1], Bf_b[i], 0} x32
//   [128..255] B1q
//   [256..383] B2q
//   [384..415] spAout[32]
//   [448..449] grad_ref (Bo_w omitted on both sides -> cancels)
//  uint view:
//   [512..2559] B-fragment table: [mv(4)][u(2)][lane(64)] x 4 uints (8 fp16)
//   fragment slot s8 (0..7) of lane l: k = 16*(s8>>2) + 4*(l>>4) + (s8&3), n = 16*u + (l&15)

// softplus + sigmoid from one exp2: t = e^{-|x|}
__device__ __forceinline__ void sp_sig(float x, float& sp, float& sig) {
    float t = __builtin_amdgcn_exp2f(-fabsf(x) * LOG2E_F);
    float u = 1.0f + t;
    float r = __builtin_amdgcn_rcpf(u);
    sp = fmaf(__builtin_amdgcn_logf(u), LN2_F, fmaxf(x, 0.0f));
    sig = (x >= 0.0f) ? r : t * r;
}

__device__ __forceinline__ float sp_only(float x) {
    float t = __builtin_amdgcn_exp2f(-fabsf(x) * LOG2E_F);
    return fmaf(__builtin_amdgcn_logf(1.0f + t), LN2_F, fmaxf(x, 0.0f));
}

__device__ __forceinline__ float sig_only(float x) {
    float t = __builtin_amdgcn_exp2f(-fabsf(x) * LOG2E_F);
    float r = __builtin_amdgcn_rcpf(1.0f + t);
    return (x >= 0.0f) ? r : t * r;
}

__global__ void prep_kernel(const float* __restrict__ Bf_w, const float* __restrict__ Bf_b,
                            const float* __restrict__ A1,
                            const float* __restrict__ B1_w, const float* __restrict__ B1_b,
                            const float* __restrict__ A2,
                            const float* __restrict__ B2_w, const float* __restrict__ B2_b,
                            const float* __restrict__ A_out,
                            float* __restrict__ ws)
{
    __shared__ float sA1[1024], sA2[1024], sAout[32];
    __shared__ float vbufA[32], vbufB[32];
    __shared__ float part0[32], part1[32];
    const int tid = threadIdx.x;  // 64 threads, 1 block

    for (int e = tid; e < 1024; e += 64) {
        sA1[e] = sp_only(A1[e]);
        sA2[e] = sp_only(A2[e]);
    }
    if (tid < 32) {
        float ao = sp_only(A_out[tid]);
        sAout[tid] = ao;
        ws[384 + tid] = ao;
        ws[4 * tid]       = Bf_w[2 * tid];
        ws[4 * tid + 1]   = Bf_w[2 * tid + 1];
        ws[4 * tid + 2]   = Bf_b[tid];
        ws[4 * tid + 3]   = 0.f;
        ws[128 + 4 * tid]     = B1_w[2 * tid];
        ws[128 + 4 * tid + 1] = B1_w[2 * tid + 1];
        ws[128 + 4 * tid + 2] = B1_b[tid];
        ws[128 + 4 * tid + 3] = 0.f;
        ws[256 + 4 * tid]     = B2_w[2 * tid];
        ws[256 + 4 * tid + 1] = B2_w[2 * tid + 1];
        ws[256 + 4 * tid + 2] = B2_b[tid];
        ws[256 + 4 * tid + 3] = 0.f;
    }
    __syncthreads();

    // ---- B-fragment table (fp16) ----
    unsigned int* wsu = (unsigned int*)ws;
    for (int e = tid; e < 512; e += 64) {
        const int mv = e >> 7, u = (e >> 6) & 1, ln = e & 63;
        const int g = ln >> 4, c = ln & 15, n = 16 * u + c;
        for (int q = 0; q < 4; ++q) {
            unsigned int word = 0;
            for (int h = 0; h < 2; ++h) {
                const int s8 = 2 * q + h;
                const int k = 16 * (s8 >> 2) + 4 * g + (s8 & 3);
                float v;
                if (mv == 0)      v = sA1[n * 32 + k];
                else if (mv == 1) v = sA2[n * 32 + k];
                else if (mv == 2) v = sA2[k * 32 + n];
                else              v = sA1[k * 32 + n];
                unsigned short hb = __half_as_ushort(__float2half(v));
                word |= ((unsigned int)hb) << (16 * h);
            }
            wsu[512 + 4 * e + q] = word;
        }
    }

    // ---- grad_ref at z0 = 0 ----
    const int i = tid;
    float su1 = 0.f, g1 = 0.f, sb1 = 0.f;
    if (tid < 32) {
        float h0;
        sp_sig(Bf_b[i], h0, su1);
        vbufA[i] = h0;
    }
    __syncthreads();
    if (tid < 32) {
        float a1 = 0.f;
        for (int j = 0; j < 32; ++j) a1 = fmaf(vbufA[j], sA1[i * 32 + j], a1);
        float s1, sa1; sp_sig(a1, s1, sa1);
        g1 = 2.0f * ACT_SCALE_F * s1 * sa1;
        float spb1; sp_sig(B1_b[i], spb1, sb1);
        vbufB[i] = fmaf(ACT_SCALE_F * s1, s1, spb1);   // z1
    }
    __syncthreads();
    if (tid < 32) {
        float a2 = 0.f;
        for (int j = 0; j < 32; ++j) a2 = fmaf(vbufB[j], sA2[i * 32 + j], a2);
        float s2, sa2; sp_sig(a2, s2, sa2);
        float g2 = 2.0f * ACT_SCALE_F * s2 * sa2;
        float sb2 = sig_only(B2_b[i]);
        float ao = sAout[i];
        part0[i] = ao * sb2 * B2_w[i * 2 + 0];
        part1[i] = ao * sb2 * B2_w[i * 2 + 1];
        vbufA[i] = ao * g2;   // v2
    }
    __syncthreads();
    if (tid < 32) {
        float dz1 = 0.f;
        for (int ii = 0; ii < 32; ++ii) dz1 = fmaf(vbufA[ii], sA2[ii * 32 + i], dz1);
        part0[i] += dz1 * sb1 * B1_w[i * 2 + 0];
        part1[i] += dz1 * sb1 * B1_w[i * 2 + 1];
        vbufB[i] = dz1 * g1;   // v1
    }
    __syncthreads();
    if (tid < 32) {
        float dh0 = 0.f;
        for (int ii = 0; ii < 32; ++ii) dh0 = fmaf(vbufB[ii], sA1[ii * 32 + i], dh0);
        part0[i] += dh0 * su1 * Bf_w[i * 2 + 0];
        part1[i] += dh0 * su1 * Bf_w[i * 2 + 1];
    }
    __syncthreads();
    if (tid == 0) {
        float r0 = 0.f, r1 = 0.f;
        for (int j = 0; j < 32; ++j) { r0 += part0[j]; r1 += part1[j]; }
        ws[448] = r0;
        ws[449] = r1;
    }
}

// One wave-level matvec: D[64 samples][32 out] = A(staged fp16) x B(frag regs), via 8 MFMA.
__device__ __forceinline__ void mfma_phase(const half8* __restrict__ Afr,
                                           float* __restrict__ Dw,
                                           const half8* __restrict__ bf,
                                           int g, int c)
{
    f32x4 d[4][2];
    #pragma unroll
    for (int t = 0; t < 4; ++t)
        #pragma unroll
        for (int u = 0; u < 2; ++u)
            d[t][u] = (f32x4){0.f, 0.f, 0.f, 0.f};
    #pragma unroll
    for (int t = 0; t < 4; ++t) {
        half8 a = Afr[(16 * t + c) * 4 + g];
        #pragma unroll
        for (int u = 0; u < 2; ++u)
            d[t][u] = __builtin_amdgcn_mfma_f32_16x16x32_f16(a, bf[u], d[t][u], 0, 0, 0);
    }
    #pragma unroll
    for (int t = 0; t < 4; ++t)
        #pragma unroll
        for (int u = 0; u < 2; ++u)
            #pragma unroll
            for (int r = 0; r < 4; ++r)
                Dw[(16 * u + c) * 67 + 16 * t + 4 * g + r] = d[t][u][r];
}

// Stage loop: for each of 16 fp16x2 words, compute values at compile-time k0,k1 via the body
// (reads/writes only static-indexed arrays), pack, then 4x ds_write_b128.
// Variadic: interior commas in the body are swallowed by __VA_ARGS__.
#define STAGE_A(...) do {                                                       \
    unsigned int rb[16];                                                        \
    _Pragma("unroll")                                                           \
    for (int w = 0; w < 16; ++w) {                                              \
        const int k0 = 16 * ((w >> 1) & 1) + 4 * (w >> 2) + 2 * (w & 1);        \
        const int k1 = k0 + 1;                                                  \
        float va, vbv;                                                          \
        { const int k = k0; float& vout = va;  __VA_ARGS__ }                    \
        { const int k = k1; float& vout = vbv; __VA_ARGS__ }                    \
        __half2 p = __floats2half2_rn(va, vbv);                                 \
        rb[w] = __builtin_bit_cast(unsigned int, p);                            \
    }                                                                           \
    _Pragma("unroll")                                                           \
    for (int q4 = 0; q4 < 4; ++q4)                                              \
        ((uint4v*)Arow)[q4] = (uint4v){rb[4*q4], rb[4*q4+1], rb[4*q4+2], rb[4*q4+3]}; \
} while (0)

__global__ void __launch_bounds__(128) icnn_main(
    const float* __restrict__ eps,
    const float* __restrict__ ws,
    float* __restrict__ out, int n)
{
    __shared__ unsigned int Au[2 * 1024];   // [wave][64 samples][16 words] fp16x2, k-permuted
    __shared__ float Dbuf[2 * 2144];        // [wave][32 out][67-padded sample]

    const int tid = threadIdx.x;
    const int wid = tid >> 6;
    const int lane = tid & 63;
    const int g = lane >> 4, c = lane & 15;

    int idx = blockIdx.x * 128 + tid;
    if (idx >= n) idx = n - 1;              // branchless clamp

    const float4* __restrict__ Bfq = (const float4*)(ws);
    const float4* __restrict__ B1q = (const float4*)(ws + 128);
    const float4* __restrict__ B2q = (const float4*)(ws + 256);
    const float* __restrict__ Aout = ws + 384;

    // B-fragments: 8 x 16B, live in VGPRs for the whole kernel
    const uint4v* __restrict__ ft = (const uint4v*)((const unsigned int*)ws + 512);
    half8 bfr[4][2];
    #pragma unroll
    for (int mv = 0; mv < 4; ++mv)
        #pragma unroll
        for (int u = 0; u < 2; ++u)
            bfr[mv][u] = __builtin_bit_cast(half8, ft[(mv * 2 + u) * 64 + lane]);

    const float gr0 = ws[448];
    const float gr1 = ws[449];

    const float e11 = eps[3 * idx + 0];
    const float e22 = eps[3 * idx + 1];
    const float e12 = eps[3 * idx + 2];
    const float I1 = e11 + e22;
    const float I2 = e11 * e11 + 2.f * e12 * e12 + e22 * e22;

    unsigned int* __restrict__ Arow = Au + wid * 1024 + lane * 16;
    const half8* __restrict__ Afr = (const half8*)(Au + wid * 1024);
    float* __restrict__ Dw = Dbuf + wid * 2144;

    float acc[32], g1[32];
    float gx0 = 0.f, gx1 = 0.f;

    // ---- L0: h0 = sp(z0 @ Bf_w.T + Bf_b) -> stage ----
    STAGE_A({
        const float4 q = Bfq[k];
        vout = sp_only(fmaf(I1, q.x, fmaf(I2, q.y, q.z)));
    });
    __syncthreads();
    mfma_phase(Afr, Dw, bfr[0], g, c);      // a1 = spA1 @ h0
    __syncthreads();
    #pragma unroll
    for (int o = 0; o < 32; ++o) acc[o] = Dw[o * 67 + lane];

    // ---- L1: keep g1; z1 -> stage ----
    STAGE_A({
        float s1, sa1;
        sp_sig(acc[k], s1, sa1);
        g1[k] = (2.0f * ACT_SCALE_F) * s1 * sa1;
        const float4 q = B1q[k];
        vout = fmaf(ACT_SCALE_F * s1, s1, sp_only(fmaf(I1, q.x, fmaf(I2, q.y, q.z))));
    });
    __syncthreads();
    mfma_phase(Afr, Dw, bfr[1], g, c);      // a2 = spA2 @ z1
    __syncthreads();
    #pragma unroll
    for (int o = 0; o < 32; ++o) acc[o] = Dw[o * 67 + lane];

    // ---- L2: B2 grad contribution; v2 -> stage ----
    STAGE_A({
        float s2, sa2;
        sp_sig(acc[k], s2, sa2);
        float g2 = (2.0f * ACT_SCALE_F) * s2 * sa2;
        const float4 q = B2q[k];
        float sb2 = sig_only(fmaf(I1, q.x, fmaf(I2, q.y, q.z)));
        float ao = Aout[k];
        float t = ao * sb2;
        gx0 = fmaf(t, q.x, gx0);
        gx1 = fmaf(t, q.y, gx1);
        vout = ao * g2;
    });
    __syncthreads();
    mfma_phase(Afr, Dw, bfr[2], g, c);      // dz1 = v2 @ spA2 (row-major)
    __syncthreads();
    #pragma unroll
    for (int o = 0; o < 32; ++o) acc[o] = Dw[o * 67 + lane];

    // ---- bwd L1: B1 grad contribution; v1/64 -> stage (fp16 range) ----
    STAGE_A({
        const float4 q = B1q[k];
        float sb1 = sig_only(fmaf(I1, q.x, fmaf(I2, q.y, q.z)));
        float t = acc[k] * sb1;
        gx0 = fmaf(t, q.x, gx0);
        gx1 = fmaf(t, q.y, gx1);
        vout = acc[k] * g1[k] * (1.0f / 64.0f);
    });
    __syncthreads();
    mfma_phase(Afr, Dw, bfr[3], g, c);      // dh0/64 = v1/64 @ spA1 (row-major)
    __syncthreads();
    #pragma unroll
    for (int o = 0; o < 32; ++o) acc[o] = Dw[o * 67 + lane];

    // ---- bwd L0: Bf grad contribution (x64 to undo scale) ----
    float gf0 = 0.f, gf1 = 0.f;
    #pragma unroll
    for (int k = 0; k < 32; ++k) {
        const float4 q = Bfq[k];
        float su1 = sig_only(fmaf(I1, q.x, fmaf(I2, q.y, q.z)));
        float t = acc[k] * su1;
        gf0 = fmaf(t, q.x, gf0);
        gf1 = fmaf(t, q.y, gf1);
    }
    gx0 = fmaf(64.f, gf0, gx0);
    gx1 = fmaf(64.f, gf1, gx1);

    const float dI1 = gx0 - gr0;
    const float dI2 = gx1 - gr1;
    out[3 * idx + 0] = fmaf(2.f * e11, dI2, dI1);
    out[3 * idx + 1] = fmaf(2.f * e22, dI2, dI1);
    out[3 * idx + 2] = 2.f * e12 * dI2;
}

extern "C" void kernel_launch(void* const* d_in, const int* in_sizes, int n_in,
                              void* d_out, int out_size, void* d_ws, size_t ws_size,
                              hipStream_t stream)
{
    const float* eps   = (const float*)d_in[0];
    const float* Bf_w  = (const float*)d_in[1];
    const float* Bf_b  = (const float*)d_in[2];
    const float* A1    = (const float*)d_in[3];
    const float* B1_w  = (const float*)d_in[4];
    const float* B1_b  = (const float*)d_in[5];
    const float* A2    = (const float*)d_in[6];
    const float* B2_w  = (const float*)d_in[7];
    const float* B2_b  = (const float*)d_in[8];
    const float* A_out = (const float*)d_in[9];
    // d_in[10] = Bo_w (cancels in grads - grad_ref), d_in[11] = Bo_b (no grad)

    float* ws  = (float*)d_ws;
    float* out = (float*)d_out;
    const int n = in_sizes[0] / 3;

    prep_kernel<<<1, 64, 0, stream>>>(Bf_w, Bf_b, A1, B1_w, B1_b, A2, B2_w, B2_b, A_out, ws);
    const int blocks = (n + 127) / 128;
    icnn_main<<<blocks, 128, 0, stream>>>(eps, ws, out, n);
}

// Round 8
// 183.480 us; speedup vs baseline: 3.8916x; 1.0492x over previous
//
#include <hip/hip_runtime.h>
#include <hip/hip_fp16.h>
#include <math.h>

#define ACT_SCALE_F (1.0f / 12.0f)
#define LOG2E_F 1.44269504088896340736f
#define LN2_F   0.69314718055994530942f

typedef __attribute__((ext_vector_type(8))) _Float16 half8;
typedef __attribute__((ext_vector_type(4))) float f32x4;
typedef __attribute__((ext_vector_type(4))) unsigned int uint4v;

// ws layout:
//  float view:
//   [0..127]   Bfq quads {Bf_w[2i], Bf_w[2i+1], Bf_b[i], 0} x32
//   [128..255] B1q
//   [256..383] B2q
//   [384..415] spAout[32]
//   [448..449] grad_ref (Bo_w omitted on both sides -> cancels)
//  uint view:
//   [512..2559] B-fragment table: [mv(4)][u(2)][lane(64)] x 4 uints (8 fp16)
//   fragment slot s8 (0..7) of lane l: k = 16*(s8>>2) + 4*(l>>4) + (s8&3), n = 16*u + (l&15)
//   (R6-proven layout; DO NOT change A/B mapping and staging independently)

__device__ __forceinline__ void sp_sig(float x, float& sp, float& sig) {
    float t = __builtin_amdgcn_exp2f(-fabsf(x) * LOG2E_F);
    float u = 1.0f + t;
    float r = __builtin_amdgcn_rcpf(u);
    sp = fmaf(__builtin_amdgcn_logf(u), LN2_F, fmaxf(x, 0.0f));
    sig = (x >= 0.0f) ? r : t * r;
}

__device__ __forceinline__ float sp_only(float x) {
    float t = __builtin_amdgcn_exp2f(-fabsf(x) * LOG2E_F);
    return fmaf(__builtin_amdgcn_logf(1.0f + t), LN2_F, fmaxf(x, 0.0f));
}

__device__ __forceinline__ float sig_only(float x) {
    float t = __builtin_amdgcn_exp2f(-fabsf(x) * LOG2E_F);
    float r = __builtin_amdgcn_rcpf(1.0f + t);
    return (x >= 0.0f) ? r : t * r;
}

__global__ void prep_kernel(const float* __restrict__ Bf_w, const float* __restrict__ Bf_b,
                            const float* __restrict__ A1,
                            const float* __restrict__ B1_w, const float* __restrict__ B1_b,
                            const float* __restrict__ A2,
                            const float* __restrict__ B2_w, const float* __restrict__ B2_b,
                            const float* __restrict__ A_out,
                            float* __restrict__ ws)
{
    __shared__ float sA1[1024], sA2[1024], sAout[32];
    __shared__ float vbufA[32], vbufB[32];
    __shared__ float part0[32], part1[32];
    const int tid = threadIdx.x;  // 64 threads, 1 block

    for (int e = tid; e < 1024; e += 64) {
        sA1[e] = sp_only(A1[e]);
        sA2[e] = sp_only(A2[e]);
    }
    if (tid < 32) {
        float ao = sp_only(A_out[tid]);
        sAout[tid] = ao;
        ws[384 + tid] = ao;
        ws[4 * tid]       = Bf_w[2 * tid];
        ws[4 * tid + 1]   = Bf_w[2 * tid + 1];
        ws[4 * tid + 2]   = Bf_b[tid];
        ws[4 * tid + 3]   = 0.f;
        ws[128 + 4 * tid]     = B1_w[2 * tid];
        ws[128 + 4 * tid + 1] = B1_w[2 * tid + 1];
        ws[128 + 4 * tid + 2] = B1_b[tid];
        ws[128 + 4 * tid + 3] = 0.f;
        ws[256 + 4 * tid]     = B2_w[2 * tid];
        ws[256 + 4 * tid + 1] = B2_w[2 * tid + 1];
        ws[256 + 4 * tid + 2] = B2_b[tid];
        ws[256 + 4 * tid + 3] = 0.f;
    }
    __syncthreads();

    // ---- B-fragment table (fp16) ----
    unsigned int* wsu = (unsigned int*)ws;
    for (int e = tid; e < 512; e += 64) {
        const int mv = e >> 7, u = (e >> 6) & 1, ln = e & 63;
        const int g = ln >> 4, c = ln & 15, n = 16 * u + c;
        for (int q = 0; q < 4; ++q) {
            unsigned int word = 0;
            for (int h = 0; h < 2; ++h) {
                const int s8 = 2 * q + h;
                const int k = 16 * (s8 >> 2) + 4 * g + (s8 & 3);
                float v;
                if (mv == 0)      v = sA1[n * 32 + k];
                else if (mv == 1) v = sA2[n * 32 + k];
                else if (mv == 2) v = sA2[k * 32 + n];
                else              v = sA1[k * 32 + n];
                unsigned short hb = __half_as_ushort(__float2half(v));
                word |= ((unsigned int)hb) << (16 * h);
            }
            wsu[512 + 4 * e + q] = word;
        }
    }

    // ---- grad_ref at z0 = 0 ----
    const int i = tid;
    float su1 = 0.f, g1 = 0.f, sb1 = 0.f;
    if (tid < 32) {
        float h0;
        sp_sig(Bf_b[i], h0, su1);
        vbufA[i] = h0;
    }
    __syncthreads();
    if (tid < 32) {
        float a1 = 0.f;
        for (int j = 0; j < 32; ++j) a1 = fmaf(vbufA[j], sA1[i * 32 + j], a1);
        float s1, sa1; sp_sig(a1, s1, sa1);
        g1 = 2.0f * ACT_SCALE_F * s1 * sa1;
        float spb1; sp_sig(B1_b[i], spb1, sb1);
        vbufB[i] = fmaf(ACT_SCALE_F * s1, s1, spb1);   // z1
    }
    __syncthreads();
    if (tid < 32) {
        float a2 = 0.f;
        for (int j = 0; j < 32; ++j) a2 = fmaf(vbufB[j], sA2[i * 32 + j], a2);
        float s2, sa2; sp_sig(a2, s2, sa2);
        float g2 = 2.0f * ACT_SCALE_F * s2 * sa2;
        float sb2 = sig_only(B2_b[i]);
        float ao = sAout[i];
        part0[i] = ao * sb2 * B2_w[i * 2 + 0];
        part1[i] = ao * sb2 * B2_w[i * 2 + 1];
        vbufA[i] = ao * g2;   // v2
    }
    __syncthreads();
    if (tid < 32) {
        float dz1 = 0.f;
        for (int ii = 0; ii < 32; ++ii) dz1 = fmaf(vbufA[ii], sA2[ii * 32 + i], dz1);
        part0[i] += dz1 * sb1 * B1_w[i * 2 + 0];
        part1[i] += dz1 * sb1 * B1_w[i * 2 + 1];
        vbufB[i] = dz1 * g1;   // v1
    }
    __syncthreads();
    if (tid < 32) {
        float dh0 = 0.f;
        for (int ii = 0; ii < 32; ++ii) dh0 = fmaf(vbufB[ii], sA1[ii * 32 + i], dh0);
        part0[i] += dh0 * su1 * Bf_w[i * 2 + 0];
        part1[i] += dh0 * su1 * Bf_w[i * 2 + 1];
    }
    __syncthreads();
    if (tid == 0) {
        float r0 = 0.f, r1 = 0.f;
        for (int j = 0; j < 32; ++j) { r0 += part0[j]; r1 += part1[j]; }
        ws[448] = r0;
        ws[449] = r1;
    }
}

// One wave-level matvec: D[64 samples][32 out] = A(staged fp16) x B(frag regs), via 8 MFMA.
// A rows padded to 20 words (80 B): read base (20c+4g) mod 32 spreads bank quads (vs 8-way at 16).
__device__ __forceinline__ void mfma_phase(const unsigned int* __restrict__ AuW,
                                           float* __restrict__ Dw,
                                           const half8* __restrict__ bf,
                                           int g, int c)
{
    f32x4 d[4][2];
    #pragma unroll
    for (int t = 0; t < 4; ++t)
        #pragma unroll
        for (int u = 0; u < 2; ++u)
            d[t][u] = (f32x4){0.f, 0.f, 0.f, 0.f};
    #pragma unroll
    for (int t = 0; t < 4; ++t) {
        half8 a = *(const half8*)(AuW + (16 * t + c) * 20 + 4 * g);
        #pragma unroll
        for (int u = 0; u < 2; ++u)
            d[t][u] = __builtin_amdgcn_mfma_f32_16x16x32_f16(a, bf[u], d[t][u], 0, 0, 0);
    }
    #pragma unroll
    for (int t = 0; t < 4; ++t)
        #pragma unroll
        for (int u = 0; u < 2; ++u)
            #pragma unroll
            for (int r = 0; r < 4; ++r)
                Dw[(16 * u + c) * 67 + 16 * t + 4 * g + r] = d[t][u][r];
}

// Stage loop: for each of 16 fp16x2 words, compute values at compile-time k0,k1 via the body
// (reads/writes only static-indexed arrays), pack, then 4x ds_write_b128.
#define STAGE_A(...) do {                                                       \
    unsigned int rb[16];                                                        \
    _Pragma("unroll")                                                           \
    for (int w = 0; w < 16; ++w) {                                              \
        const int k0 = 16 * ((w >> 1) & 1) + 4 * (w >> 2) + 2 * (w & 1);        \
        const int k1 = k0 + 1;                                                  \
        float va, vbv;                                                          \
        { const int k = k0; float& vout = va;  __VA_ARGS__ }                    \
        { const int k = k1; float& vout = vbv; __VA_ARGS__ }                    \
        __half2 p = __floats2half2_rn(va, vbv);                                 \
        rb[w] = __builtin_bit_cast(unsigned int, p);                            \
    }                                                                           \
    _Pragma("unroll")                                                           \
    for (int q4 = 0; q4 < 4; ++q4)                                              \
        ((uint4v*)Arow)[q4] = (uint4v){rb[4*q4], rb[4*q4+1], rb[4*q4+2], rb[4*q4+3]}; \
} while (0)

__global__ void __launch_bounds__(128) icnn_main(
    const float* __restrict__ eps,
    const float* __restrict__ ws,
    float* __restrict__ out, int n)
{
    __shared__ unsigned int Au[2 * 1280];   // [wave][64 samples][20 words] fp16x2, k-permuted, padded
    __shared__ float Dbuf[2 * 2144];        // [wave][32 out][67-padded sample]

    const int tid = threadIdx.x;
    const int wid = tid >> 6;
    const int lane = tid & 63;
    const int g = lane >> 4, c = lane & 15;

    int idx = blockIdx.x * 128 + tid;
    if (idx >= n) idx = n - 1;              // branchless clamp

    const float4* __restrict__ Bfq = (const float4*)(ws);
    const float4* __restrict__ B1q = (const float4*)(ws + 128);
    const float4* __restrict__ B2q = (const float4*)(ws + 256);
    const float* __restrict__ Aout = ws + 384;

    // B-fragments: 8 x 16B, live in VGPRs for the whole kernel
    const uint4v* __restrict__ ft = (const uint4v*)((const unsigned int*)ws + 512);
    half8 bfr[4][2];
    #pragma unroll
    for (int mv = 0; mv < 4; ++mv)
        #pragma unroll
        for (int u = 0; u < 2; ++u)
            bfr[mv][u] = __builtin_bit_cast(half8, ft[(mv * 2 + u) * 64 + lane]);

    const float gr0 = ws[448];
    const float gr1 = ws[449];

    const float e11 = eps[3 * idx + 0];
    const float e22 = eps[3 * idx + 1];
    const float e12 = eps[3 * idx + 2];
    const float I1 = e11 + e22;
    const float I2 = e11 * e11 + 2.f * e12 * e12 + e22 * e22;

    unsigned int* __restrict__ Arow = Au + wid * 1280 + lane * 20;
    const unsigned int* __restrict__ AuW = Au + wid * 1280;
    float* __restrict__ Dw = Dbuf + wid * 2144;

    float acc[32], g1[32];
    float gx0 = 0.f, gx1 = 0.f;

    // ---- L0: h0 = sp(z0 @ Bf_w.T + Bf_b) -> stage ----
    STAGE_A({
        const float4 q = Bfq[k];
        vout = sp_only(fmaf(I1, q.x, fmaf(I2, q.y, q.z)));
    });
    __syncthreads();
    mfma_phase(AuW, Dw, bfr[0], g, c);      // a1 = spA1 @ h0
    __syncthreads();
    #pragma unroll
    for (int o = 0; o < 32; ++o) acc[o] = Dw[o * 67 + lane];

    // ---- L1: keep g1; z1 -> stage ----
    STAGE_A({
        float s1, sa1;
        sp_sig(acc[k], s1, sa1);
        g1[k] = (2.0f * ACT_SCALE_F) * s1 * sa1;
        const float4 q = B1q[k];
        vout = fmaf(ACT_SCALE_F * s1, s1, sp_only(fmaf(I1, q.x, fmaf(I2, q.y, q.z))));
    });
    __syncthreads();
    mfma_phase(AuW, Dw, bfr[1], g, c);      // a2 = spA2 @ z1
    __syncthreads();
    #pragma unroll
    for (int o = 0; o < 32; ++o) acc[o] = Dw[o * 67 + lane];

    // ---- L2: B2 grad contribution; v2 -> stage ----
    STAGE_A({
        float s2, sa2;
        sp_sig(acc[k], s2, sa2);
        float g2 = (2.0f * ACT_SCALE_F) * s2 * sa2;
        const float4 q = B2q[k];
        float sb2 = sig_only(fmaf(I1, q.x, fmaf(I2, q.y, q.z)));
        float ao = Aout[k];
        float t = ao * sb2;
        gx0 = fmaf(t, q.x, gx0);
        gx1 = fmaf(t, q.y, gx1);
        vout = ao * g2;
    });
    __syncthreads();
    mfma_phase(AuW, Dw, bfr[2], g, c);      // dz1 = v2 @ spA2 (row-major)
    __syncthreads();
    #pragma unroll
    for (int o = 0; o < 32; ++o) acc[o] = Dw[o * 67 + lane];

    // ---- bwd L1: B1 grad contribution; v1/64 -> stage (fp16 range) ----
    STAGE_A({
        const float4 q = B1q[k];
        float sb1 = sig_only(fmaf(I1, q.x, fmaf(I2, q.y, q.z)));
        float t = acc[k] * sb1;
        gx0 = fmaf(t, q.x, gx0);
        gx1 = fmaf(t, q.y, gx1);
        vout = acc[k] * g1[k] * (1.0f / 64.0f);
    });
    __syncthreads();
    mfma_phase(AuW, Dw, bfr[3], g, c);      // dh0/64 = v1/64 @ spA1 (row-major)
    __syncthreads();
    #pragma unroll
    for (int o = 0; o < 32; ++o) acc[o] = Dw[o * 67 + lane];

    // ---- bwd L0: Bf grad contribution (x64 to undo scale) ----
    float gf0 = 0.f, gf1 = 0.f;
    #pragma unroll
    for (int k = 0; k < 32; ++k) {
        const float4 q = Bfq[k];
        float su1 = sig_only(fmaf(I1, q.x, fmaf(I2, q.y, q.z)));
        float t = acc[k] * su1;
        gf0 = fmaf(t, q.x, gf0);
        gf1 = fmaf(t, q.y, gf1);
    }
    gx0 = fmaf(64.f, gf0, gx0);
    gx1 = fmaf(64.f, gf1, gx1);

    const float dI1 = gx0 - gr0;
    const float dI2 = gx1 - gr1;
    out[3 * idx + 0] = fmaf(2.f * e11, dI2, dI1);
    out[3 * idx + 1] = fmaf(2.f * e22, dI2, dI1);
    out[3 * idx + 2] = 2.f * e12 * dI2;
}

extern "C" void kernel_launch(void* const* d_in, const int* in_sizes, int n_in,
                              void* d_out, int out_size, void* d_ws, size_t ws_size,
                              hipStream_t stream)
{
    const float* eps   = (const float*)d_in[0];
    const float* Bf_w  = (const float*)d_in[1];
    const float* Bf_b  = (const float*)d_in[2];
    const float* A1    = (const float*)d_in[3];
    const float* B1_w  = (const float*)d_in[4];
    const float* B1_b  = (const float*)d_in[5];
    const float* A2    = (const float*)d_in[6];
    const float* B2_w  = (const float*)d_in[7];
    const float* B2_b  = (const float*)d_in[8];
    const float* A_out = (const float*)d_in[9];
    // d_in[10] = Bo_w (cancels in grads - grad_ref), d_in[11] = Bo_b (no grad)

    float* ws  = (float*)d_ws;
    float* out = (float*)d_out;
    const int n = in_sizes[0] / 3;

    prep_kernel<<<1, 64, 0, stream>>>(Bf_w, Bf_b, A1, B1_w, B1_b, A2, B2_w, B2_b, A_out, ws);
    const int blocks = (n + 127) / 128;
    icnn_main<<<blocks, 128, 0, stream>>>(eps, ws, out, n);
}

// Round 9
// 143.556 us; speedup vs baseline: 4.9739x; 1.2781x over previous
//
#include <hip/hip_runtime.h>
#include <hip/hip_fp16.h>
#include <math.h>

#define ACT_SCALE_F (1.0f / 12.0f)
#define LOG2E_F 1.44269504088896340736f
#define LN2_F   0.69314718055994530942f

typedef __attribute__((ext_vector_type(8))) _Float16 half8;
typedef __attribute__((ext_vector_type(4))) float f32x4;
typedef __attribute__((ext_vector_type(4))) unsigned int uint4v;
typedef __attribute__((ext_vector_type(2))) unsigned int uint2v;

// ws layout:
//  float view:
//   [0..127]   Bfq quads {Bf_w[2i], Bf_w[2i+1], Bf_b[i], 0} x32
//   [128..255] B1q
//   [256..383] B2q
//   [384..415] spAout[32]
//   [448..449] grad_ref (Bo_w omitted on both sides -> cancels)
//  uint view:
//   [512..2559] B-fragment table: [mv(4)][u(2)][lane(64)] x 4 uints (8 fp16)
//   fragment slot s8 (0..7) of lane l: k = 16*(s8>>2) + 4*(l>>4) + (s8&3), n = 16*u + (l&15)
//   (R6/R8-proven layout; DO NOT change A/B mapping and staging independently)

__device__ __forceinline__ void sp_sig(float x, float& sp, float& sig) {
    float t = __builtin_amdgcn_exp2f(-fabsf(x) * LOG2E_F);
    float u = 1.0f + t;
    float r = __builtin_amdgcn_rcpf(u);
    sp = fmaf(__builtin_amdgcn_logf(u), LN2_F, fmaxf(x, 0.0f));
    sig = (x >= 0.0f) ? r : t * r;
}

__device__ __forceinline__ float sp_only(float x) {
    float t = __builtin_amdgcn_exp2f(-fabsf(x) * LOG2E_F);
    return fmaf(__builtin_amdgcn_logf(1.0f + t), LN2_F, fmaxf(x, 0.0f));
}

__device__ __forceinline__ float sig_only(float x) {
    float t = __builtin_amdgcn_exp2f(-fabsf(x) * LOG2E_F);
    float r = __builtin_amdgcn_rcpf(1.0f + t);
    return (x >= 0.0f) ? r : t * r;
}

__global__ void prep_kernel(const float* __restrict__ Bf_w, const float* __restrict__ Bf_b,
                            const float* __restrict__ A1,
                            const float* __restrict__ B1_w, const float* __restrict__ B1_b,
                            const float* __restrict__ A2,
                            const float* __restrict__ B2_w, const float* __restrict__ B2_b,
                            const float* __restrict__ A_out,
                            float* __restrict__ ws)
{
    __shared__ float sA1[1024], sA2[1024], sAout[32];
    __shared__ float vbufA[32], vbufB[32];
    __shared__ float part0[32], part1[32];
    const int tid = threadIdx.x;  // 64 threads, 1 block

    for (int e = tid; e < 1024; e += 64) {
        sA1[e] = sp_only(A1[e]);
        sA2[e] = sp_only(A2[e]);
    }
    if (tid < 32) {
        float ao = sp_only(A_out[tid]);
        sAout[tid] = ao;
        ws[384 + tid] = ao;
        ws[4 * tid]       = Bf_w[2 * tid];
        ws[4 * tid + 1]   = Bf_w[2 * tid + 1];
        ws[4 * tid + 2]   = Bf_b[tid];
        ws[4 * tid + 3]   = 0.f;
        ws[128 + 4 * tid]     = B1_w[2 * tid];
        ws[128 + 4 * tid + 1] = B1_w[2 * tid + 1];
        ws[128 + 4 * tid + 2] = B1_b[tid];
        ws[128 + 4 * tid + 3] = 0.f;
        ws[256 + 4 * tid]     = B2_w[2 * tid];
        ws[256 + 4 * tid + 1] = B2_w[2 * tid + 1];
        ws[256 + 4 * tid + 2] = B2_b[tid];
        ws[256 + 4 * tid + 3] = 0.f;
    }
    __syncthreads();

    // ---- B-fragment table (fp16) ----
    unsigned int* wsu = (unsigned int*)ws;
    for (int e = tid; e < 512; e += 64) {
        const int mv = e >> 7, u = (e >> 6) & 1, ln = e & 63;
        const int g = ln >> 4, c = ln & 15, n = 16 * u + c;
        for (int q = 0; q < 4; ++q) {
            unsigned int word = 0;
            for (int h = 0; h < 2; ++h) {
                const int s8 = 2 * q + h;
                const int k = 16 * (s8 >> 2) + 4 * g + (s8 & 3);
                float v;
                if (mv == 0)      v = sA1[n * 32 + k];
                else if (mv == 1) v = sA2[n * 32 + k];
                else if (mv == 2) v = sA2[k * 32 + n];
                else              v = sA1[k * 32 + n];
                unsigned short hb = __half_as_ushort(__float2half(v));
                word |= ((unsigned int)hb) << (16 * h);
            }
            wsu[512 + 4 * e + q] = word;
        }
    }

    // ---- grad_ref at z0 = 0 ----
    const int i = tid;
    float su1 = 0.f, g1 = 0.f, sb1 = 0.f;
    if (tid < 32) {
        float h0;
        sp_sig(Bf_b[i], h0, su1);
        vbufA[i] = h0;
    }
    __syncthreads();
    if (tid < 32) {
        float a1 = 0.f;
        for (int j = 0; j < 32; ++j) a1 = fmaf(vbufA[j], sA1[i * 32 + j], a1);
        float s1, sa1; sp_sig(a1, s1, sa1);
        g1 = 2.0f * ACT_SCALE_F * s1 * sa1;
        float spb1; sp_sig(B1_b[i], spb1, sb1);
        vbufB[i] = fmaf(ACT_SCALE_F * s1, s1, spb1);   // z1
    }
    __syncthreads();
    if (tid < 32) {
        float a2 = 0.f;
        for (int j = 0; j < 32; ++j) a2 = fmaf(vbufB[j], sA2[i * 32 + j], a2);
        float s2, sa2; sp_sig(a2, s2, sa2);
        float g2 = 2.0f * ACT_SCALE_F * s2 * sa2;
        float sb2 = sig_only(B2_b[i]);
        float ao = sAout[i];
        part0[i] = ao * sb2 * B2_w[i * 2 + 0];
        part1[i] = ao * sb2 * B2_w[i * 2 + 1];
        vbufA[i] = ao * g2;   // v2
    }
    __syncthreads();
    if (tid < 32) {
        float dz1 = 0.f;
        for (int ii = 0; ii < 32; ++ii) dz1 = fmaf(vbufA[ii], sA2[ii * 32 + i], dz1);
        part0[i] += dz1 * sb1 * B1_w[i * 2 + 0];
        part1[i] += dz1 * sb1 * B1_w[i * 2 + 1];
        vbufB[i] = dz1 * g1;   // v1
    }
    __syncthreads();
    if (tid < 32) {
        float dh0 = 0.f;
        for (int ii = 0; ii < 32; ++ii) dh0 = fmaf(vbufB[ii], sA1[ii * 32 + i], dh0);
        part0[i] += dh0 * su1 * Bf_w[i * 2 + 0];
        part1[i] += dh0 * su1 * Bf_w[i * 2 + 1];
    }
    __syncthreads();
    if (tid == 0) {
        float r0 = 0.f, r1 = 0.f;
        for (int j = 0; j < 32; ++j) { r0 += part0[j]; r1 += part1[j]; }
        ws[448] = r0;
        ws[449] = r1;
    }
}

// One wave-level matvec: D[64 samples][32 out] = A(staged fp16) x B(frag regs), via 8 MFMA.
// D written fp16 to Dw rows stride 68 halfs (8B-aligned b64 writes; b16 readback conflict-free).
__device__ __forceinline__ void mfma_phase(const unsigned int* __restrict__ AuW,
                                           __half* __restrict__ Dw,
                                           half8 b0, half8 b1,
                                           int g, int c)
{
    const f32x4 z4 = {0.f, 0.f, 0.f, 0.f};
    #pragma unroll
    for (int t = 0; t < 4; ++t) {
        half8 a = *(const half8*)(AuW + (16 * t + c) * 20 + 4 * g);
        f32x4 d0 = __builtin_amdgcn_mfma_f32_16x16x32_f16(a, b0, z4, 0, 0, 0);
        f32x4 d1 = __builtin_amdgcn_mfma_f32_16x16x32_f16(a, b1, z4, 0, 0, 0);
        __half2 p00 = __floats2half2_rn(d0[0], d0[1]);
        __half2 p01 = __floats2half2_rn(d0[2], d0[3]);
        __half2 p10 = __floats2half2_rn(d1[0], d1[1]);
        __half2 p11 = __floats2half2_rn(d1[2], d1[3]);
        *(uint2v*)(Dw + c * 68 + 16 * t + 4 * g) =
            (uint2v){__builtin_bit_cast(unsigned int, p00), __builtin_bit_cast(unsigned int, p01)};
        *(uint2v*)(Dw + (16 + c) * 68 + 16 * t + 4 * g) =
            (uint2v){__builtin_bit_cast(unsigned int, p10), __builtin_bit_cast(unsigned int, p11)};
    }
}

// Stage loop: for each of 16 fp16x2 words, compute values at compile-time k0,k1 via the body
// (reads/writes only static-indexed arrays), pack, then 4x ds_write_b128.
#define STAGE_A(...) do {                                                       \
    unsigned int rb[16];                                                        \
    _Pragma("unroll")                                                           \
    for (int w = 0; w < 16; ++w) {                                              \
        const int k0 = 16 * ((w >> 1) & 1) + 4 * (w >> 2) + 2 * (w & 1);        \
        const int k1 = k0 + 1;                                                  \
        float va, vbv;                                                          \
        { const int k = k0; float& vout = va;  __VA_ARGS__ }                    \
        { const int k = k1; float& vout = vbv; __VA_ARGS__ }                    \
        __half2 p = __floats2half2_rn(va, vbv);                                 \
        rb[w] = __builtin_bit_cast(unsigned int, p);                            \
    }                                                                           \
    _Pragma("unroll")                                                           \
    for (int q4 = 0; q4 < 4; ++q4)                                              \
        ((uint4v*)Arow)[q4] = (uint4v){rb[4*q4], rb[4*q4+1], rb[4*q4+2], rb[4*q4+3]}; \
} while (0)

// No __syncthreads in the main kernel: Au and Dh slices are strictly per-wave
// private (wid-indexed); intra-wave LDS ordering is guaranteed by compiler
// lgkmcnt waits (alias-visible through the same base pointers).
__global__ void __launch_bounds__(128) icnn_main(
    const float* __restrict__ eps,
    const float* __restrict__ ws,
    float* __restrict__ out, int n)
{
    __shared__ unsigned int Au[2 * 1280];   // [wave][64 samples][20 words] fp16x2, k-permuted, padded
    __shared__ __half Dh[2 * 2176];         // [wave][32 out][68-padded sample] fp16

    const int tid = threadIdx.x;
    const int wid = tid >> 6;
    const int lane = tid & 63;
    const int g = lane >> 4, c = lane & 15;

    int idx = blockIdx.x * 128 + tid;
    if (idx >= n) idx = n - 1;              // branchless clamp

    const float4* __restrict__ Bfq = (const float4*)(ws);
    const float4* __restrict__ B1q = (const float4*)(ws + 128);
    const float4* __restrict__ B2q = (const float4*)(ws + 256);
    const float* __restrict__ Aout = ws + 384;
    const uint4v* __restrict__ ft = (const uint4v*)((const unsigned int*)ws + 512);

    const float gr0 = ws[448];
    const float gr1 = ws[449];

    const float e11 = eps[3 * idx + 0];
    const float e22 = eps[3 * idx + 1];
    const float e12 = eps[3 * idx + 2];
    const float I1 = e11 + e22;
    const float I2 = e11 * e11 + 2.f * e12 * e12 + e22 * e22;

    unsigned int* __restrict__ Arow = Au + wid * 1280 + lane * 20;
    const unsigned int* __restrict__ AuW = Au + wid * 1280;
    __half* __restrict__ Dw = Dh + wid * 2176;

    float acc[32], g1[32];
    float gx0 = 0.f, gx1 = 0.f;

    // ---- L0: h0 = sp(z0 @ Bf_w.T + Bf_b) -> stage ----
    STAGE_A({
        const float4 q = Bfq[k];
        vout = sp_only(fmaf(I1, q.x, fmaf(I2, q.y, q.z)));
    });
    {   // a1 = spA1 @ h0
        half8 b0 = __builtin_bit_cast(half8, ft[0 * 64 + lane]);
        half8 b1 = __builtin_bit_cast(half8, ft[1 * 64 + lane]);
        mfma_phase(AuW, Dw, b0, b1, g, c);
    }
    #pragma unroll
    for (int o = 0; o < 32; ++o) acc[o] = __half2float(Dw[o * 68 + lane]);

    // ---- L1: keep g1; z1 -> stage ----
    STAGE_A({
        float s1, sa1;
        sp_sig(acc[k], s1, sa1);
        g1[k] = (2.0f * ACT_SCALE_F) * s1 * sa1;
        const float4 q = B1q[k];
        vout = fmaf(ACT_SCALE_F * s1, s1, sp_only(fmaf(I1, q.x, fmaf(I2, q.y, q.z))));
    });
    {   // a2 = spA2 @ z1
        half8 b0 = __builtin_bit_cast(half8, ft[2 * 64 + lane]);
        half8 b1 = __builtin_bit_cast(half8, ft[3 * 64 + lane]);
        mfma_phase(AuW, Dw, b0, b1, g, c);
    }
    #pragma unroll
    for (int o = 0; o < 32; ++o) acc[o] = __half2float(Dw[o * 68 + lane]);

    // ---- L2: B2 grad contribution; v2 -> stage ----
    STAGE_A({
        float s2, sa2;
        sp_sig(acc[k], s2, sa2);
        float g2 = (2.0f * ACT_SCALE_F) * s2 * sa2;
        const float4 q = B2q[k];
        float sb2 = sig_only(fmaf(I1, q.x, fmaf(I2, q.y, q.z)));
        float ao = Aout[k];
        float t = ao * sb2;
        gx0 = fmaf(t, q.x, gx0);
        gx1 = fmaf(t, q.y, gx1);
        vout = ao * g2;
    });
    {   // dz1 = v2 @ spA2 (row-major)
        half8 b0 = __builtin_bit_cast(half8, ft[4 * 64 + lane]);
        half8 b1 = __builtin_bit_cast(half8, ft[5 * 64 + lane]);
        mfma_phase(AuW, Dw, b0, b1, g, c);
    }
    #pragma unroll
    for (int o = 0; o < 32; ++o) acc[o] = __half2float(Dw[o * 68 + lane]);

    // ---- bwd L1: B1 grad contribution; v1/64 -> stage (fp16 range) ----
    STAGE_A({
        const float4 q = B1q[k];
        float sb1 = sig_only(fmaf(I1, q.x, fmaf(I2, q.y, q.z)));
        float t = acc[k] * sb1;
        gx0 = fmaf(t, q.x, gx0);
        gx1 = fmaf(t, q.y, gx1);
        vout = acc[k] * g1[k] * (1.0f / 64.0f);
    });
    {   // dh0/64 = v1/64 @ spA1 (row-major)
        half8 b0 = __builtin_bit_cast(half8, ft[6 * 64 + lane]);
        half8 b1 = __builtin_bit_cast(half8, ft[7 * 64 + lane]);
        mfma_phase(AuW, Dw, b0, b1, g, c);
    }
    #pragma unroll
    for (int o = 0; o < 32; ++o) acc[o] = __half2float(Dw[o * 68 + lane]);

    // ---- bwd L0: Bf grad contribution (x64 to undo scale) ----
    float gf0 = 0.f, gf1 = 0.f;
    #pragma unroll
    for (int k = 0; k < 32; ++k) {
        const float4 q = Bfq[k];
        float su1 = sig_only(fmaf(I1, q.x, fmaf(I2, q.y, q.z)));
        float t = acc[k] * su1;
        gf0 = fmaf(t, q.x, gf0);
        gf1 = fmaf(t, q.y, gf1);
    }
    gx0 = fmaf(64.f, gf0, gx0);
    gx1 = fmaf(64.f, gf1, gx1);

    const float dI1 = gx0 - gr0;
    const float dI2 = gx1 - gr1;
    out[3 * idx + 0] = fmaf(2.f * e11, dI2, dI1);
    out[3 * idx + 1] = fmaf(2.f * e22, dI2, dI1);
    out[3 * idx + 2] = 2.f * e12 * dI2;
}

extern "C" void kernel_launch(void* const* d_in, const int* in_sizes, int n_in,
                              void* d_out, int out_size, void* d_ws, size_t ws_size,
                              hipStream_t stream)
{
    const float* eps   = (const float*)d_in[0];
    const float* Bf_w  = (const float*)d_in[1];
    const float* Bf_b  = (const float*)d_in[2];
    const float* A1    = (const float*)d_in[3];
    const float* B1_w  = (const float*)d_in[4];
    const float* B1_b  = (const float*)d_in[5];
    const float* A2    = (const float*)d_in[6];
    const float* B2_w  = (const float*)d_in[7];
    const float* B2_b  = (const float*)d_in[8];
    const float* A_out = (const float*)d_in[9];
    // d_in[10] = Bo_w (cancels in grads - grad_ref), d_in[11] = Bo_b (no grad)

    float* ws  = (float*)d_ws;
    float* out = (float*)d_out;
    const int n = in_sizes[0] / 3;

    prep_kernel<<<1, 64, 0, stream>>>(Bf_w, Bf_b, A1, B1_w, B1_b, A2, B2_w, B2_b, A_out, ws);
    const int blocks = (n + 127) / 128;
    icnn_main<<<blocks, 128, 0, stream>>>(eps, ws, out, n);
}

// Round 10
// 132.713 us; speedup vs baseline: 5.3803x; 1.0817x over previous
//
#include <hip/hip_runtime.h>
#include <hip/hip_fp16.h>
#include <math.h>

#define ACT_SCALE_F (1.0f / 12.0f)
#define LOG2E_F 1.44269504088896340736f
#define LN2_F   0.69314718055994530942f

typedef __attribute__((ext_vector_type(8))) _Float16 half8;
typedef __attribute__((ext_vector_type(4))) float f32x4;
typedef __attribute__((ext_vector_type(4))) unsigned int uint4v;
typedef __attribute__((ext_vector_type(2))) unsigned int uint2v;

// ws layout:
//  float view:
//   [0..127]   Bfq quads {Bf_w[2i], Bf_w[2i+1], Bf_b[i], 0} x32
//   [128..255] B1q
//   [256..383] B2q
//   [384..415] spAout[32]
//   [448..449] grad_ref (Bo_w omitted on both sides -> cancels)
//  uint view:
//   [512..2559] B-fragment table: [mv(4)][u(2)][lane(64)] x 4 uints (8 fp16)
//   fragment slot s8 (0..7) of lane l: k = 16*(s8>>2) + 4*(l>>4) + (s8&3), n = 16*u + (l&15)
//   (R6/R8/R9-proven layout; DO NOT change A/B mapping and staging independently)

__device__ __forceinline__ void sp_sig(float x, float& sp, float& sig) {
    float t = __builtin_amdgcn_exp2f(-fabsf(x) * LOG2E_F);
    float u = 1.0f + t;
    float r = __builtin_amdgcn_rcpf(u);
    sp = fmaf(__builtin_amdgcn_logf(u), LN2_F, fmaxf(x, 0.0f));
    sig = (x >= 0.0f) ? r : t * r;
}

__device__ __forceinline__ float sp_only(float x) {
    float t = __builtin_amdgcn_exp2f(-fabsf(x) * LOG2E_F);
    return fmaf(__builtin_amdgcn_logf(1.0f + t), LN2_F, fmaxf(x, 0.0f));
}

__device__ __forceinline__ float sig_only(float x) {
    float t = __builtin_amdgcn_exp2f(-fabsf(x) * LOG2E_F);
    float r = __builtin_amdgcn_rcpf(1.0f + t);
    return (x >= 0.0f) ? r : t * r;
}

__global__ void prep_kernel(const float* __restrict__ Bf_w, const float* __restrict__ Bf_b,
                            const float* __restrict__ A1,
                            const float* __restrict__ B1_w, const float* __restrict__ B1_b,
                            const float* __restrict__ A2,
                            const float* __restrict__ B2_w, const float* __restrict__ B2_b,
                            const float* __restrict__ A_out,
                            float* __restrict__ ws)
{
    __shared__ float sA1[1024], sA2[1024], sAout[32];
    __shared__ float vbufA[32], vbufB[32];
    __shared__ float part0[32], part1[32];
    const int tid = threadIdx.x;  // 64 threads, 1 block

    for (int e = tid; e < 1024; e += 64) {
        sA1[e] = sp_only(A1[e]);
        sA2[e] = sp_only(A2[e]);
    }
    if (tid < 32) {
        float ao = sp_only(A_out[tid]);
        sAout[tid] = ao;
        ws[384 + tid] = ao;
        ws[4 * tid]       = Bf_w[2 * tid];
        ws[4 * tid + 1]   = Bf_w[2 * tid + 1];
        ws[4 * tid + 2]   = Bf_b[tid];
        ws[4 * tid + 3]   = 0.f;
        ws[128 + 4 * tid]     = B1_w[2 * tid];
        ws[128 + 4 * tid + 1] = B1_w[2 * tid + 1];
        ws[128 + 4 * tid + 2] = B1_b[tid];
        ws[128 + 4 * tid + 3] = 0.f;
        ws[256 + 4 * tid]     = B2_w[2 * tid];
        ws[256 + 4 * tid + 1] = B2_w[2 * tid + 1];
        ws[256 + 4 * tid + 2] = B2_b[tid];
        ws[256 + 4 * tid + 3] = 0.f;
    }
    __syncthreads();

    // ---- B-fragment table (fp16) ----
    unsigned int* wsu = (unsigned int*)ws;
    for (int e = tid; e < 512; e += 64) {
        const int mv = e >> 7, u = (e >> 6) & 1, ln = e & 63;
        const int g = ln >> 4, c = ln & 15, n = 16 * u + c;
        for (int q = 0; q < 4; ++q) {
            unsigned int word = 0;
            for (int h = 0; h < 2; ++h) {
                const int s8 = 2 * q + h;
                const int k = 16 * (s8 >> 2) + 4 * g + (s8 & 3);
                float v;
                if (mv == 0)      v = sA1[n * 32 + k];
                else if (mv == 1) v = sA2[n * 32 + k];
                else if (mv == 2) v = sA2[k * 32 + n];
                else              v = sA1[k * 32 + n];
                unsigned short hb = __half_as_ushort(__float2half(v));
                word |= ((unsigned int)hb) << (16 * h);
            }
            wsu[512 + 4 * e + q] = word;
        }
    }

    // ---- grad_ref at z0 = 0 ----
    const int i = tid;
    float su1 = 0.f, g1 = 0.f, sb1 = 0.f;
    if (tid < 32) {
        float h0;
        sp_sig(Bf_b[i], h0, su1);
        vbufA[i] = h0;
    }
    __syncthreads();
    if (tid < 32) {
        float a1 = 0.f;
        for (int j = 0; j < 32; ++j) a1 = fmaf(vbufA[j], sA1[i * 32 + j], a1);
        float s1, sa1; sp_sig(a1, s1, sa1);
        g1 = 2.0f * ACT_SCALE_F * s1 * sa1;
        float spb1; sp_sig(B1_b[i], spb1, sb1);
        vbufB[i] = fmaf(ACT_SCALE_F * s1, s1, spb1);   // z1
    }
    __syncthreads();
    if (tid < 32) {
        float a2 = 0.f;
        for (int j = 0; j < 32; ++j) a2 = fmaf(vbufB[j], sA2[i * 32 + j], a2);
        float s2, sa2; sp_sig(a2, s2, sa2);
        float g2 = 2.0f * ACT_SCALE_F * s2 * sa2;
        float sb2 = sig_only(B2_b[i]);
        float ao = sAout[i];
        part0[i] = ao * sb2 * B2_w[i * 2 + 0];
        part1[i] = ao * sb2 * B2_w[i * 2 + 1];
        vbufA[i] = ao * g2;   // v2
    }
    __syncthreads();
    if (tid < 32) {
        float dz1 = 0.f;
        for (int ii = 0; ii < 32; ++ii) dz1 = fmaf(vbufA[ii], sA2[ii * 32 + i], dz1);
        part0[i] += dz1 * sb1 * B1_w[i * 2 + 0];
        part1[i] += dz1 * sb1 * B1_w[i * 2 + 1];
        vbufB[i] = dz1 * g1;   // v1
    }
    __syncthreads();
    if (tid < 32) {
        float dh0 = 0.f;
        for (int ii = 0; ii < 32; ++ii) dh0 = fmaf(vbufB[ii], sA1[ii * 32 + i], dh0);
        part0[i] += dh0 * su1 * Bf_w[i * 2 + 0];
        part1[i] += dh0 * su1 * Bf_w[i * 2 + 1];
    }
    __syncthreads();
    if (tid == 0) {
        float r0 = 0.f, r1 = 0.f;
        for (int j = 0; j < 32; ++j) { r0 += part0[j]; r1 += part1[j]; }
        ws[448] = r0;
        ws[449] = r1;
    }
}

// One wave-level matvec: D[64 samples][32 out] = A(staged fp16) x B(frag regs), via 8 MFMA.
// D written fp16 to Dw rows stride 68 halfs (8B-aligned b64 writes; b16 readback conflict-free).
__device__ __forceinline__ void mfma_phase(const unsigned int* __restrict__ AuW,
                                           __half* __restrict__ Dw,
                                           half8 b0, half8 b1,
                                           int g, int c)
{
    const f32x4 z4 = {0.f, 0.f, 0.f, 0.f};
    #pragma unroll
    for (int t = 0; t < 4; ++t) {
        half8 a = *(const half8*)(AuW + (16 * t + c) * 20 + 4 * g);
        f32x4 d0 = __builtin_amdgcn_mfma_f32_16x16x32_f16(a, b0, z4, 0, 0, 0);
        f32x4 d1 = __builtin_amdgcn_mfma_f32_16x16x32_f16(a, b1, z4, 0, 0, 0);
        __half2 p00 = __floats2half2_rn(d0[0], d0[1]);
        __half2 p01 = __floats2half2_rn(d0[2], d0[3]);
        __half2 p10 = __floats2half2_rn(d1[0], d1[1]);
        __half2 p11 = __floats2half2_rn(d1[2], d1[3]);
        *(uint2v*)(Dw + c * 68 + 16 * t + 4 * g) =
            (uint2v){__builtin_bit_cast(unsigned int, p00), __builtin_bit_cast(unsigned int, p01)};
        *(uint2v*)(Dw + (16 + c) * 68 + 16 * t + 4 * g) =
            (uint2v){__builtin_bit_cast(unsigned int, p10), __builtin_bit_cast(unsigned int, p11)};
    }
}

// Stage loop: for each of 16 fp16x2 words, compute values at compile-time k0,k1 via the body
// (reads/writes only static-indexed arrays), pack, then 4x ds_write_b128.
#define STAGE_A(...) do {                                                       \
    unsigned int rb[16];                                                        \
    _Pragma("unroll")                                                           \
    for (int w = 0; w < 16; ++w) {                                              \
        const int k0 = 16 * ((w >> 1) & 1) + 4 * (w >> 2) + 2 * (w & 1);        \
        const int k1 = k0 + 1;                                                  \
        float va, vbv;                                                          \
        { const int k = k0; float& vout = va;  __VA_ARGS__ }                    \
        { const int k = k1; float& vout = vbv; __VA_ARGS__ }                    \
        __half2 p = __floats2half2_rn(va, vbv);                                 \
        rb[w] = __builtin_bit_cast(unsigned int, p);                            \
    }                                                                           \
    _Pragma("unroll")                                                           \
    for (int q4 = 0; q4 < 4; ++q4)                                              \
        ((uint4v*)Arow)[q4] = (uint4v){rb[4*q4], rb[4*q4+1], rb[4*q4+2], rb[4*q4+3]}; \
} while (0)

// SINGLE-WAVE workgroup (R10 change): 1 wave per block -> 16 independent
// blocks/CU (LDS 9472 B each), saturating the VGPR-allowed 4 waves/SIMD.
// No __syncthreads: all LDS is wave-private; intra-wave ordering via lgkmcnt.
__global__ void __launch_bounds__(64) icnn_main(
    const float* __restrict__ eps,
    const float* __restrict__ ws,
    float* __restrict__ out, int n)
{
    __shared__ unsigned int Au[1280];   // [64 samples][20 words] fp16x2, k-permuted, padded
    __shared__ __half Dh[2176];         // [32 out][68-padded sample] fp16

    const int lane = threadIdx.x;       // 64 threads = 1 wave
    const int g = lane >> 4, c = lane & 15;

    int idx = blockIdx.x * 64 + lane;
    if (idx >= n) idx = n - 1;          // branchless clamp

    const float4* __restrict__ Bfq = (const float4*)(ws);
    const float4* __restrict__ B1q = (const float4*)(ws + 128);
    const float4* __restrict__ B2q = (const float4*)(ws + 256);
    const float* __restrict__ Aout = ws + 384;
    const uint4v* __restrict__ ft = (const uint4v*)((const unsigned int*)ws + 512);

    const float gr0 = ws[448];
    const float gr1 = ws[449];

    const float e11 = eps[3 * idx + 0];
    const float e22 = eps[3 * idx + 1];
    const float e12 = eps[3 * idx + 2];
    const float I1 = e11 + e22;
    const float I2 = e11 * e11 + 2.f * e12 * e12 + e22 * e22;

    unsigned int* __restrict__ Arow = Au + lane * 20;
    const unsigned int* __restrict__ AuW = Au;
    __half* __restrict__ Dw = Dh;

    float acc[32], g1[32];
    float gx0 = 0.f, gx1 = 0.f;

    // ---- L0: h0 = sp(z0 @ Bf_w.T + Bf_b) -> stage ----
    STAGE_A({
        const float4 q = Bfq[k];
        vout = sp_only(fmaf(I1, q.x, fmaf(I2, q.y, q.z)));
    });
    {   // a1 = spA1 @ h0
        half8 b0 = __builtin_bit_cast(half8, ft[0 * 64 + lane]);
        half8 b1 = __builtin_bit_cast(half8, ft[1 * 64 + lane]);
        mfma_phase(AuW, Dw, b0, b1, g, c);
    }
    #pragma unroll
    for (int o = 0; o < 32; ++o) acc[o] = __half2float(Dw[o * 68 + lane]);

    // ---- L1: keep g1; z1 -> stage ----
    STAGE_A({
        float s1, sa1;
        sp_sig(acc[k], s1, sa1);
        g1[k] = (2.0f * ACT_SCALE_F) * s1 * sa1;
        const float4 q = B1q[k];
        vout = fmaf(ACT_SCALE_F * s1, s1, sp_only(fmaf(I1, q.x, fmaf(I2, q.y, q.z))));
    });
    {   // a2 = spA2 @ z1
        half8 b0 = __builtin_bit_cast(half8, ft[2 * 64 + lane]);
        half8 b1 = __builtin_bit_cast(half8, ft[3 * 64 + lane]);
        mfma_phase(AuW, Dw, b0, b1, g, c);
    }
    #pragma unroll
    for (int o = 0; o < 32; ++o) acc[o] = __half2float(Dw[o * 68 + lane]);

    // ---- L2: B2 grad contribution; v2 -> stage ----
    STAGE_A({
        float s2, sa2;
        sp_sig(acc[k], s2, sa2);
        float g2 = (2.0f * ACT_SCALE_F) * s2 * sa2;
        const float4 q = B2q[k];
        float sb2 = sig_only(fmaf(I1, q.x, fmaf(I2, q.y, q.z)));
        float ao = Aout[k];
        float t = ao * sb2;
        gx0 = fmaf(t, q.x, gx0);
        gx1 = fmaf(t, q.y, gx1);
        vout = ao * g2;
    });
    {   // dz1 = v2 @ spA2 (row-major)
        half8 b0 = __builtin_bit_cast(half8, ft[4 * 64 + lane]);
        half8 b1 = __builtin_bit_cast(half8, ft[5 * 64 + lane]);
        mfma_phase(AuW, Dw, b0, b1, g, c);
    }
    #pragma unroll
    for (int o = 0; o < 32; ++o) acc[o] = __half2float(Dw[o * 68 + lane]);

    // ---- bwd L1: B1 grad contribution; v1/64 -> stage (fp16 range) ----
    STAGE_A({
        const float4 q = B1q[k];
        float sb1 = sig_only(fmaf(I1, q.x, fmaf(I2, q.y, q.z)));
        float t = acc[k] * sb1;
        gx0 = fmaf(t, q.x, gx0);
        gx1 = fmaf(t, q.y, gx1);
        vout = acc[k] * g1[k] * (1.0f / 64.0f);
    });
    {   // dh0/64 = v1/64 @ spA1 (row-major)
        half8 b0 = __builtin_bit_cast(half8, ft[6 * 64 + lane]);
        half8 b1 = __builtin_bit_cast(half8, ft[7 * 64 + lane]);
        mfma_phase(AuW, Dw, b0, b1, g, c);
    }
    #pragma unroll
    for (int o = 0; o < 32; ++o) acc[o] = __half2float(Dw[o * 68 + lane]);

    // ---- bwd L0: Bf grad contribution (x64 to undo scale) ----
    float gf0 = 0.f, gf1 = 0.f;
    #pragma unroll
    for (int k = 0; k < 32; ++k) {
        const float4 q = Bfq[k];
        float su1 = sig_only(fmaf(I1, q.x, fmaf(I2, q.y, q.z)));
        float t = acc[k] * su1;
        gf0 = fmaf(t, q.x, gf0);
        gf1 = fmaf(t, q.y, gf1);
    }
    gx0 = fmaf(64.f, gf0, gx0);
    gx1 = fmaf(64.f, gf1, gx1);

    const float dI1 = gx0 - gr0;
    const float dI2 = gx1 - gr1;
    out[3 * idx + 0] = fmaf(2.f * e11, dI2, dI1);
    out[3 * idx + 1] = fmaf(2.f * e22, dI2, dI1);
    out[3 * idx + 2] = 2.f * e12 * dI2;
}

extern "C" void kernel_launch(void* const* d_in, const int* in_sizes, int n_in,
                              void* d_out, int out_size, void* d_ws, size_t ws_size,
                              hipStream_t stream)
{
    const float* eps   = (const float*)d_in[0];
    const float* Bf_w  = (const float*)d_in[1];
    const float* Bf_b  = (const float*)d_in[2];
    const float* A1    = (const float*)d_in[3];
    const float* B1_w  = (const float*)d_in[4];
    const float* B1_b  = (const float*)d_in[5];
    const float* A2    = (const float*)d_in[6];
    const float* B2_w  = (const float*)d_in[7];
    const float* B2_b  = (const float*)d_in[8];
    const float* A_out = (const float*)d_in[9];
    // d_in[10] = Bo_w (cancels in grads - grad_ref), d_in[11] = Bo_b (no grad)

    float* ws  = (float*)d_ws;
    float* out = (float*)d_out;
    const int n = in_sizes[0] / 3;

    prep_kernel<<<1, 64, 0, stream>>>(Bf_w, Bf_b, A1, B1_w, B1_b, A2, B2_w, B2_b, A_out, ws);
    const int blocks = (n + 63) / 64;
    icnn_main<<<blocks, 64, 0, stream>>>(eps, ws, out, n);
}